// Round 9
// baseline (1571.439 us; speedup 1.0000x reference)
//
#include <hip/hip_runtime.h>
#include <hip/hip_bf16.h>
#include <stdint.h>

#define N_USER 100000
#define N_ITEM 50000
#define NTOT   150000
#define NEDGE  1200000
#define D      64
#define OUTD   256
#define NEG    0.01f
#define NBLK   586    // ceil(150000/256)
#define LSTR   65     // fp32 LDS row stride (floats)
#define SSTR   72     // bf16 LDS row stride (shorts): 144B = 9*16 -> aligned b128, <=2-way
#define INITBLK 9375  // NTOT*16/256 exact
#define HISTBLK 4688  // ceil(NEDGE/256)
#define WPREPBLK 24   // 6144 weight-fragment short8s / 256

typedef __attribute__((ext_vector_type(8))) short short8;
typedef __attribute__((ext_vector_type(4))) float f32x4;

// fp32 -> bf16 (RNE), returns the 16-bit pattern.
__device__ inline ushort f2bf(float x) {
    uint32_t u = __float_as_uint(x);
    u += 0x7fffu + ((u >> 16) & 1u);
    return (ushort)(u >> 16);
}
// x ~= hi + lo with hi,lo bf16. Combined rel error ~2^-17.
__device__ inline void split2(float x, ushort& h, ushort& l) {
    ushort hh = f2bf(x);
    float hf = __uint_as_float(((uint32_t)hh) << 16);
    h = hh;
    l = f2bf(x - hf);
}
// Load 8 contiguous floats, produce hi/lo bf16 fragments.
__device__ inline void split8(const float* p, short8& h8, short8& l8) {
    float4 v0 = *(const float4*)p;
    float4 v1 = *(const float4*)(p + 4);
    float vv[8] = {v0.x, v0.y, v0.z, v0.w, v1.x, v1.y, v1.z, v1.w};
    #pragma unroll
    for (int e = 0; e < 8; e++) {
        ushort h, l;
        split2(vv[e], h, l);
        h8[e] = (short)h; l8[e] = (short)l;
    }
}

// Fused one-time prep: E0 init + out chunk 0; edge histogram; weight pre-split.
// Weight fragment array (ushort): u = ((((L*2+m)*64+col)*2+s)*4+kg)*2+p, 8 shorts each.
__global__ void k_init_hist(const float* __restrict__ ue, const float* __restrict__ ie,
                            float* __restrict__ E, float* __restrict__ out,
                            const int* __restrict__ row, int* __restrict__ cnt,
                            const float* __restrict__ Wf, const float* __restrict__ Wb,
                            ushort* __restrict__ wpre) {
    if (blockIdx.x < INITBLK) {
        int t = blockIdx.x * 256 + threadIdx.x;     // exactly NTOT*16 threads
        int r = t >> 4, q = t & 15;
        const float* src = (r < N_USER) ? (ue + (size_t)r * D)
                                        : (ie + (size_t)(r - N_USER) * D);
        float4 v = *(const float4*)(src + q * 4);
        *(float4*)(E + (size_t)r * D + q * 4) = v;
        *(float4*)(out + (size_t)r * OUTD + q * 4) = v;
    } else if (blockIdx.x < INITBLK + HISTBLK) {
        int e = (blockIdx.x - INITBLK) * 256 + threadIdx.x;
        if (e < NEDGE) atomicAdd(&cnt[row[e]], 1);
    } else {
        int u = (blockIdx.x - INITBLK - HISTBLK) * 256 + threadIdx.x;
        if (u < 6144) {
            int p  = u & 1;
            int kg = (u >> 1) & 3;
            int s  = (u >> 3) & 1;
            int c  = (u >> 4) & 63;
            int m  = (u >> 10) & 1;
            int L  = u >> 11;
            const float* W = m ? Wb : Wf;
            const float* src = W + (size_t)L * 4096 + c * 64 + s * 32 + kg * 8;
            short8 h8, l8;
            split8(src, h8, l8);
            *(short8*)(wpre + (size_t)u * 8) = p ? l8 : h8;   // wpre 16B-aligned (layout)
        }
    }
}

// Phase A: per-block (256) partial sums of counts
__global__ void k_scan_a(const int* __restrict__ cnt, int* __restrict__ part) {
    __shared__ int s[4];
    int i = blockIdx.x * 256 + threadIdx.x;
    int v = (i < NTOT) ? cnt[i] : 0;
    for (int off = 32; off; off >>= 1) v += __shfl_down(v, off, 64);
    if ((threadIdx.x & 63) == 0) s[threadIdx.x >> 6] = v;
    __syncthreads();
    if (threadIdx.x == 0) part[blockIdx.x] = s[0] + s[1] + s[2] + s[3];
}

// Phase B: single-block exclusive scan of NBLK partials
__global__ void k_scan_b(int* __restrict__ part) {
    __shared__ int s[1024];
    int t = threadIdx.x;
    int v = (t < NBLK) ? part[t] : 0;
    s[t] = v;
    __syncthreads();
    for (int off = 1; off < 1024; off <<= 1) {
        int x = (t >= off) ? s[t - off] : 0;
        __syncthreads();
        s[t] += x;
        __syncthreads();
    }
    if (t < NBLK) part[t] = s[t] - v;  // exclusive
}

// Phase C: in-block exclusive scan + block base -> offsets and cursor copy
__global__ void k_scan_c(const int* __restrict__ cnt, const int* __restrict__ part,
                         int* __restrict__ offs, int* __restrict__ cur) {
    __shared__ int ws[4];
    int i = blockIdx.x * 256 + threadIdx.x;
    int v = (i < NTOT) ? cnt[i] : 0;
    int lane = threadIdx.x & 63, w = threadIdx.x >> 6;
    int x = v;
    for (int o = 1; o < 64; o <<= 1) {
        int y = __shfl_up(x, o, 64);
        if (lane >= o) x += y;
    }
    if (lane == 63) ws[w] = x;
    __syncthreads();
    int base = part[blockIdx.x];
    for (int k = 0; k < w; k++) base += ws[k];
    int excl = base + x - v;
    if (i < NTOT) { offs[i] = excl; cur[i] = excl; }
    if (i == 0) offs[NTOT] = NEDGE;
}

// Scatter edges into CSR order; pack (rowlocal<<18 | col, val).
// col < 150000 < 2^18; rowlocal = r & 15 (tiles are 16-aligned).
__global__ void k_scatter(const int* __restrict__ row, const int* __restrict__ col,
                          const float* __restrict__ val, int* __restrict__ cur,
                          int2* __restrict__ ce) {
    int e = blockIdx.x * blockDim.x + threadIdx.x;
    if (e >= NEDGE) return;
    int r = row[e];
    int p = atomicAdd(&cur[r], 1);
    int2 u;
    u.x = col[e] | ((r & 15) << 18);
    u.y = __float_as_int(val[e]);
    ce[p] = u;
}

// Fused layer: edge-parallel SpMM (LDS fp atomics) + MFMA GEMV/lrelu/norm.
//
// Round-8 fixes vs round-7 (which regressed 143us/layer):
//  (1) IMBALANCE: phase A was row-per-group; barrier waited on max of 16
//      Poisson(8) degrees. Now EDGE-PARALLEL over the block's contiguous
//      CSR range [offs[r0], offs[r0+16]) with stride-16 groups + 4-way ILP;
//      row recovered from packed bits; accumulate via LDS atomicAdd(float)
//      (ds_add_f32). Imbalance now ~ block-total edges (sigma ~9%).
//  (2) VALU: weight split8 (~400 ops/thread/block) hoisted to one-time
//      prep (wpre, 96KB, L2-hot). Row split done once by the fp32 owner
//      thread (8 split2), stored as bf16 hi/lo LDS tiles (SSTR=72 shorts:
//      16B-aligned b128 reads, <=2-way banks). Phase B = ds_read + 12 MFMA.
// Round-9 (this file): crash-defensive fixes only — wpre moved to a 16B
// boundary (was 4-mod-16: UB b128), ce padded to 8B alignment, explicit
// __align__(16) on LDS tiles.
__global__ __launch_bounds__(256) void k_layer(
    const float* __restrict__ Ecur, float* __restrict__ Enx,
    const int* __restrict__ offs, const int2* __restrict__ ce,
    const ushort* __restrict__ wpre, const float* __restrict__ bfv,
    const float* __restrict__ bbv, float* __restrict__ out, int chunk) {
    __shared__ __align__(16) float  sf [16 * LSTR];
    __shared__ __align__(16) ushort sfh[16 * SSTR], sfl[16 * SSTR];
    __shared__ __align__(16) ushort sgh[16 * SSTR], sgl[16 * SSTR];
    __shared__ __align__(16) float  nrm[16][4];

    int t    = threadIdx.x;
    int r0   = blockIdx.x * 16;
    int row  = t >> 4;          // owner row (and edge-group id)
    int lid  = t & 15;          // dim-quarter lane
    int d4   = lid * 4;

    // Seed sf with the identity term (the +I in (H+I)@E).
    float4 ei = *(const float4*)(Ecur + (size_t)(r0 + row) * D + d4);
    *(float4*)(sf + row * LSTR + d4) = ei;

    // Phase-B identity: wave w covers cols [w*16, w*16+16).
    int lane = t & 63, w = t >> 6;
    int cl   = lane & 15, kg = lane >> 4;
    int col  = w * 16 + cl;

    // Pre-split weight fragments: 8 x 16B loads, no conversion VALU.
    short8 wfh0, wfl0, wfh1, wfl1, wbh0, wbl0, wbh1, wbl1;
    {
        const ushort* bp = wpre;
        #define WLD(m, s, p) (*(const short8*)(bp + (size_t)((((((m)*64+col)*2+(s))*4+kg)*2+(p))*8)))
        wfh0 = WLD(0, 0, 0); wfl0 = WLD(0, 0, 1);
        wfh1 = WLD(0, 1, 0); wfl1 = WLD(0, 1, 1);
        wbh0 = WLD(1, 0, 0); wbl0 = WLD(1, 0, 1);
        wbh1 = WLD(1, 1, 0); wbl1 = WLD(1, 1, 1);
        #undef WLD
    }
    float bF = bfv[col], bB = bbv[col];

    __syncthreads();   // sf seeded before atomics

    // ---- Phase A: edge-parallel SpMM over the block's CSR range ----
    {
        int base = offs[r0];
        int n    = offs[r0 + 16] - base;
        int i = row;   // group id
        for (; i + 48 < n; i += 64) {
            int2 c0 = ce[base + i];
            int2 c1 = ce[base + i + 16];
            int2 c2 = ce[base + i + 32];
            int2 c3 = ce[base + i + 48];
            float4 x0 = *(const float4*)(Ecur + (size_t)(c0.x & 0x3FFFF) * D + d4);
            float4 x1 = *(const float4*)(Ecur + (size_t)(c1.x & 0x3FFFF) * D + d4);
            float4 x2 = *(const float4*)(Ecur + (size_t)(c2.x & 0x3FFFF) * D + d4);
            float4 x3 = *(const float4*)(Ecur + (size_t)(c3.x & 0x3FFFF) * D + d4);
            float v0 = __int_as_float(c0.y), v1 = __int_as_float(c1.y);
            float v2 = __int_as_float(c2.y), v3 = __int_as_float(c3.y);
            float* p0 = sf + (c0.x >> 18) * LSTR + d4;
            float* p1 = sf + (c1.x >> 18) * LSTR + d4;
            float* p2 = sf + (c2.x >> 18) * LSTR + d4;
            float* p3 = sf + (c3.x >> 18) * LSTR + d4;
            atomicAdd(p0 + 0, v0 * x0.x); atomicAdd(p0 + 1, v0 * x0.y);
            atomicAdd(p0 + 2, v0 * x0.z); atomicAdd(p0 + 3, v0 * x0.w);
            atomicAdd(p1 + 0, v1 * x1.x); atomicAdd(p1 + 1, v1 * x1.y);
            atomicAdd(p1 + 2, v1 * x1.z); atomicAdd(p1 + 3, v1 * x1.w);
            atomicAdd(p2 + 0, v2 * x2.x); atomicAdd(p2 + 1, v2 * x2.y);
            atomicAdd(p2 + 2, v2 * x2.z); atomicAdd(p2 + 3, v2 * x2.w);
            atomicAdd(p3 + 0, v3 * x3.x); atomicAdd(p3 + 1, v3 * x3.y);
            atomicAdd(p3 + 2, v3 * x3.z); atomicAdd(p3 + 3, v3 * x3.w);
        }
        for (; i < n; i += 16) {
            int2 c = ce[base + i];
            float4 x = *(const float4*)(Ecur + (size_t)(c.x & 0x3FFFF) * D + d4);
            float v = __int_as_float(c.y);
            float* p = sf + (c.x >> 18) * LSTR + d4;
            atomicAdd(p + 0, v * x.x); atomicAdd(p + 1, v * x.y);
            atomicAdd(p + 2, v * x.z); atomicAdd(p + 3, v * x.w);
        }
    }
    __syncthreads();

    // Owner thread: fr -> (fr, fr*ei) -> bf16 hi/lo tiles.
    {
        float4 fr = *(const float4*)(sf + row * LSTR + d4);
        float4 gv;
        gv.x = fr.x * ei.x; gv.y = fr.y * ei.y;
        gv.z = fr.z * ei.z; gv.w = fr.w * ei.w;
        ushort h0,l0,h1,l1,h2,l2,h3,l3;
        split2(fr.x, h0, l0); split2(fr.y, h1, l1);
        split2(fr.z, h2, l2); split2(fr.w, h3, l3);
        *(ushort4*)(sfh + row * SSTR + d4) = make_ushort4(h0, h1, h2, h3);
        *(ushort4*)(sfl + row * SSTR + d4) = make_ushort4(l0, l1, l2, l3);
        split2(gv.x, h0, l0); split2(gv.y, h1, l1);
        split2(gv.z, h2, l2); split2(gv.w, h3, l3);
        *(ushort4*)(sgh + row * SSTR + d4) = make_ushort4(h0, h1, h2, h3);
        *(ushort4*)(sgl + row * SSTR + d4) = make_ushort4(l0, l1, l2, l3);
    }
    __syncthreads();

    // ---- Phase B: MFMA double-GEMV (bf16 hi/lo, 3 passes) ----
    f32x4 accF = {0.f, 0.f, 0.f, 0.f};
    f32x4 accB = {0.f, 0.f, 0.f, 0.f};
    {
        // kstep 0: k in [0,32)
        short8 fh = *(const short8*)(sfh + cl * SSTR +  0 + kg * 8);
        short8 fl = *(const short8*)(sfl + cl * SSTR +  0 + kg * 8);
        short8 gh = *(const short8*)(sgh + cl * SSTR +  0 + kg * 8);
        short8 gl = *(const short8*)(sgl + cl * SSTR +  0 + kg * 8);
        accF = __builtin_amdgcn_mfma_f32_16x16x32_bf16(fh, wfh0, accF, 0, 0, 0);
        accB = __builtin_amdgcn_mfma_f32_16x16x32_bf16(gh, wbh0, accB, 0, 0, 0);
        accF = __builtin_amdgcn_mfma_f32_16x16x32_bf16(fl, wfh0, accF, 0, 0, 0);
        accB = __builtin_amdgcn_mfma_f32_16x16x32_bf16(gl, wbh0, accB, 0, 0, 0);
        accF = __builtin_amdgcn_mfma_f32_16x16x32_bf16(fh, wfl0, accF, 0, 0, 0);
        accB = __builtin_amdgcn_mfma_f32_16x16x32_bf16(gh, wbl0, accB, 0, 0, 0);
        // kstep 1: k in [32,64)
        fh = *(const short8*)(sfh + cl * SSTR + 32 + kg * 8);
        fl = *(const short8*)(sfl + cl * SSTR + 32 + kg * 8);
        gh = *(const short8*)(sgh + cl * SSTR + 32 + kg * 8);
        gl = *(const short8*)(sgl + cl * SSTR + 32 + kg * 8);
        accF = __builtin_amdgcn_mfma_f32_16x16x32_bf16(fh, wfh1, accF, 0, 0, 0);
        accB = __builtin_amdgcn_mfma_f32_16x16x32_bf16(gh, wbh1, accB, 0, 0, 0);
        accF = __builtin_amdgcn_mfma_f32_16x16x32_bf16(fl, wfh1, accF, 0, 0, 0);
        accB = __builtin_amdgcn_mfma_f32_16x16x32_bf16(gl, wbh1, accB, 0, 0, 0);
        accF = __builtin_amdgcn_mfma_f32_16x16x32_bf16(fh, wfl1, accF, 0, 0, 0);
        accB = __builtin_amdgcn_mfma_f32_16x16x32_bf16(gh, wbl1, accB, 0, 0, 0);
    }

    // Epilogue: bias + lrelu + sum, per-row norm across all 64 cols.
    float e4[4], p4[4];
    #pragma unroll
    for (int rg = 0; rg < 4; rg++) {
        float aF = accF[rg] + bF;
        float aB = accB[rg] + bB;
        float vF = (aF > 0.f) ? aF : NEG * aF;
        float vB = (aB > 0.f) ? aB : NEG * aB;
        float e = vF + vB;
        e4[rg] = e;
        float p = e * e;
        p += __shfl_xor(p, 1, 64);
        p += __shfl_xor(p, 2, 64);
        p += __shfl_xor(p, 4, 64);
        p += __shfl_xor(p, 8, 64);   // sum over this wave's 16 cols
        p4[rg] = p;
    }
    if (cl == 0) {
        #pragma unroll
        for (int rg = 0; rg < 4; rg++) nrm[kg * 4 + rg][w] = p4[rg];
    }
    __syncthreads();
    #pragma unroll
    for (int rg = 0; rg < 4; rg++) {
        int rr = kg * 4 + rg;
        float4 nv = *(const float4*)&nrm[rr][0];
        float nsq = (nv.x + nv.y) + (nv.z + nv.w);
        float inv = 1.0f / fmaxf(sqrtf(nsq), 1e-12f);
        Enx[(size_t)(r0 + rr) * D + col] = e4[rg];
        out[(size_t)(r0 + rr) * OUTD + (size_t)chunk * D + col] = e4[rg] * inv;
    }
}

extern "C" void kernel_launch(void* const* d_in, const int* in_sizes, int n_in,
                              void* d_out, int out_size, void* d_ws, size_t ws_size,
                              hipStream_t stream) {
    const float* ue   = (const float*)d_in[0];
    const float* ie   = (const float*)d_in[1];
    const int*   erow = (const int*)d_in[2];
    const int*   ecol = (const int*)d_in[3];
    const float* eval = (const float*)d_in[4];
    const float* Wf   = (const float*)d_in[5];
    const float* bfv  = (const float*)d_in[6];
    const float* Wb   = (const float*)d_in[7];
    const float* bbv  = (const float*)d_in[8];
    float* out = (float*)d_out;

    // Workspace layout — every vector-typed region naturally aligned:
    // E0,E1 16B; wpre 16B (96KB, right after E1); ints; offs padded to NTOT+2
    // so ce (int2) is 8B-aligned. Total ~88.3MB (round-0 layout proved >=88.8).
    float*  E0   = (float*)d_ws;                     // NTOT*D
    float*  E1   = E0 + (size_t)NTOT * D;            // NTOT*D (ping-pong)
    ushort* wpre = (ushort*)(E1 + (size_t)NTOT * D); // 49152 shorts (96KB), 16B-aligned
    int*    cnt  = (int*)(wpre + 49152);             // NTOT
    int*    offs = cnt + NTOT;                       // NTOT+2 (pad for alignment)
    int*    cur  = offs + NTOT + 2;                  // NTOT
    int*    part = cur + NTOT;                       // 1024
    int2*   ce   = (int2*)(part + 1024);             // NEDGE int2, 8B-aligned

    hipMemsetAsync(cnt, 0, NTOT * sizeof(int), stream);
    k_init_hist<<<INITBLK + HISTBLK + WPREPBLK, 256, 0, stream>>>(
        ue, ie, E0, out, erow, cnt, Wf, Wb, wpre);
    k_scan_a<<<NBLK, 256, 0, stream>>>(cnt, part);
    k_scan_b<<<1, 1024, 0, stream>>>(part);
    k_scan_c<<<NBLK, 256, 0, stream>>>(cnt, part, offs, cur);
    k_scatter<<<(NEDGE + 255) / 256, 256, 0, stream>>>(erow, ecol, eval, cur, ce);

    const float* rd[3] = {E0, E1, E0};
    float*       wr[3] = {E1, E0, E1};
    for (int i = 0; i < 3; i++) {
        k_layer<<<NTOT / 16, 256, 0, stream>>>(
            rd[i], wr[i], offs, ce,
            wpre + (size_t)i * 16384, bfv + (size_t)i * D,
            bbv + (size_t)i * D, out, i + 1);
    }
}